// Round 6
// baseline (75.984 us; speedup 1.0000x reference)
//
#include <hip/hip_runtime.h>

#define BLOCK 256
#define NWAVE 4                 // waves per block (independent; no inner-loop barriers)
#define WQ    32                // queries per wave
#define QPB   (NWAVE * WQ)      // 128 queries per block -> 720 blocks
#define CHUNK 2048              // candidates register-resident per wave: 64 lanes x 32
#define NQUAD (CHUNK / 256)     // 8 quads (of 4 candidates) per lane
#define ROWP  68                // padded row stride (floats) for epilogue transpose

// d2(q,c) = q2 + (C - 2qx*cx - 2qy*cy), C = fma(cx,cx,cy*cy). All intermediates
// for valid candidates are integer-valued fp32 < 2^24 -> every fma/mul/add is
// exact, so any association matches the reference's a2 + b2 - 2ab exactly
// (verified absmax=0 rounds 0-5, identical association kept here). Sentinel
// (x=y=3e4): partial ~1.74e9 >> max valid partial (~1.05e6) -> never wins the
// min when gate>1. sqrt and *0.01 are monotone roundings -> min commutes.
// v_pk_fma_f32 is per-lane IEEE fma -> bit-identical to scalar.

typedef float v2f __attribute__((ext_vector_type(2)));

__device__ __forceinline__ v2f pkfma(v2f a, v2f b, v2f c) {
    return __builtin_elementwise_fma(a, b, c);   // -> v_pk_fma_f32 on gfx950
}
__device__ __forceinline__ float rdlane(float v, int l) {
    return __int_as_float(__builtin_amdgcn_readlane(__float_as_int(v), l));
}

__global__ __launch_bounds__(BLOCK, 3) void gauss_kernel(
    const int* __restrict__ li_coors, int n_li,
    const int* __restrict__ ra_coors, int n_ra,
    const float* __restrict__ pts,
    const int* __restrict__ vox,
    int m,
    float* __restrict__ out, int total)
{
    // Union region: staging arrays (3*2048 floats = 24 KB) while candidates are
    // being loaded; per-wave transpose scratch (4*32*68 floats = 34 KB) in the
    // epilogue, AFTER the barrier that retires all staging readers.
    __shared__ __align__(16) float smem[NWAVE * WQ * ROWP];  // 34816 B
    __shared__ int s_cnt;

    float* __restrict__ SX = smem;              // [CHUNK]
    float* __restrict__ SY = smem + CHUNK;      // [CHUNK]
    float* __restrict__ SC = smem + 2 * CHUNK;  // [CHUNK]

    const int tid  = threadIdx.x;
    const int lane = tid & 63;
    const int w    = tid >> 6;

    if (tid == 0) s_cnt = 0;

    // ---- decode: lane L (< WQ) owns query qbase+L of this wave ----
    const int qbase = blockIdx.x * QPB + w * WQ;
    const int li_total = n_li * 9;
    float nx = 0.0f, ny = 0.0f, q2 = 0.0f;
    {
        int q = qbase + (lane & (WQ - 1));
        if (lane < WQ && q < total) {
            const int shift_x[9] = {0,-1,1,0,-1,1,0,-1,1};
            const int shift_y[9] = {0, 0,0,1, 1,1,-1,-1,-1};
            int n, s;
            const int* src;
            if (q < li_total) { n = q / 9; s = q - n * 9; src = li_coors; }
            else { int r = q - li_total; n = r / 9; s = r - n * 9; src = ra_coors; }
            int cx = src[n * 2 + 0] + shift_x[s];
            int cy = src[n * 2 + 1] + shift_y[s];
            if (cx < 0) cx += 513;   // coords in [0,511], shift in {-1,0,1}
            if (cy < 0) cy += 513;
            float qx = (float)cx, qy = (float)cy;
            nx = -2.0f * qx;
            ny = -2.0f * qy;
            q2 = fmaf(qx, qx, qy * qy);
        }
    }

    float mnq[WQ];
#pragma unroll
    for (int i = 0; i < WQ; ++i) mnq[i] = 3.4e38f;

    // candidate registers: 6 v2f arrays x NQUAD = 96 VGPRs, constant-indexed
    v2f cx01[NQUAD], cx23[NQUAD], cy01[NQUAD], cy23[NQUAD], cc01[NQUAD], cc23[NQUAD];

    for (int base = 0; base < m; base += CHUNK) {
        const int cs = min(m - base, CHUNK);

        __syncthreads();   // first: s_cnt init visible; later: regfill readers done
        for (int i = tid; i < CHUNK; i += BLOCK) {   // 8 iterations
            int gi = base + i;
            float x = 3.0e4f, y = 3.0e4f;
            bool dyn = false;
            if (i < cs && fabsf(pts[gi * 5 + 4]) > 0.1f) {
                dyn = true;
                x = (float)vox[gi * 3 + 1];
                y = (float)vox[gi * 3 + 2];
            }
            SX[i] = x;
            SY[i] = y;
            SC[i] = fmaf(x, x, y * y);
            // exact global dynamic-point count (block covers all of [base,base+cs))
            unsigned long long b = __ballot(dyn);
            if (lane == 0 && b) atomicAdd(&s_cnt, (int)__popcll(b));
        }
        __syncthreads();

        // ---- register fill: lane L takes quads L+64j (conflict-free b128) ----
        const float4* __restrict__ X4 = (const float4*)SX;
        const float4* __restrict__ Y4 = (const float4*)SY;
        const float4* __restrict__ C4 = (const float4*)SC;
#pragma unroll
        for (int j = 0; j < NQUAD; ++j) {
            float4 X = X4[lane + 64 * j];
            float4 Y = Y4[lane + 64 * j];
            float4 C = C4[lane + 64 * j];
            cx01[j] = v2f{X.x, X.y}; cx23[j] = v2f{X.z, X.w};
            cy01[j] = v2f{Y.x, Y.y}; cy23[j] = v2f{Y.z, Y.w};
            cc01[j] = v2f{C.x, C.y}; cc23[j] = v2f{C.z, C.w};
        }

        // ---- main loop: pure VALU, no memory ops, no barriers ----
        // Per query: broadcast (nx,ny) from the owning lane via v_readlane,
        // then 8 quads x (4 pk_fma + 2 min3) over lane-resident candidates.
#pragma unroll
        for (int q = 0; q < WQ; ++q) {
            float snx = rdlane(nx, q);
            float sny = rdlane(ny, q);
            v2f vnx = {snx, snx};
            v2f vny = {sny, sny};
            float mv = mnq[q];
#pragma unroll
            for (int j = 0; j < NQUAD; ++j) {
                v2f T0 = pkfma(cx01[j], vnx, pkfma(cy01[j], vny, cc01[j]));
                v2f T1 = pkfma(cx23[j], vnx, pkfma(cy23[j], vny, cc23[j]));
                mv = fminf(fminf(T0.x, T0.y), mv);   // v_min3
                mv = fminf(fminf(T1.x, T1.y), mv);   // v_min3
            }
            mnq[q] = mv;
        }
    }

    __syncthreads();   // all staging/regfill reads retired -> scratch overlay safe

    // ---- epilogue: per-wave padded transpose in LDS, 64-lane min per query ----
    float* __restrict__ wscr = smem + w * (WQ * ROWP);
#pragma unroll
    for (int q = 0; q < WQ; ++q)
        wscr[q * ROWP + lane] = mnq[q];   // lane-stride 4B: conflict-free
    // same-wave ds_write -> ds_read: compiler inserts lgkmcnt

    if (lane < WQ) {
        const float4* __restrict__ r4 = (const float4*)(wscr + lane * ROWP); // 272B rows, 16B-aligned
        float v = 3.4e38f;
#pragma unroll
        for (int j = 0; j < 16; ++j) {
            float4 t = r4[j];
            v = fminf(fminf(t.x, t.y), v);
            v = fminf(fminf(t.z, t.w), v);
        }
        int gq = qbase + lane;
        if (gq < total)
            out[gq] = (s_cnt > 1) ? sqrtf(fmaxf(q2 + v, 0.0f)) * 0.01f : 0.0f;
    }
}

extern "C" void kernel_launch(void* const* d_in, const int* in_sizes, int n_in,
                              void* d_out, int out_size, void* d_ws, size_t ws_size,
                              hipStream_t stream) {
    const int*   li  = (const int*)d_in[0];
    const int*   ra  = (const int*)d_in[1];
    const float* pts = (const float*)d_in[2];
    const int*   vox = (const int*)d_in[3];

    const int n_li = in_sizes[0] / 2;
    const int n_ra = in_sizes[1] / 2;
    const int m    = in_sizes[2] / 5;

    const int total  = (n_li + n_ra) * 9;            // 92160
    const int blocks = (total + QPB - 1) / QPB;      // 720

    gauss_kernel<<<blocks, BLOCK, 0, stream>>>(
        li, n_li, ra, n_ra, pts, vox, m, (float*)d_out, total);
}